// Round 1
// baseline (18192.358 us; speedup 1.0000x reference)
//
#include <hip/hip_runtime.h>

// ---------------------------------------------------------------------------
// Fused window cross-attention for MI355X (gfx950).
//   ref: q = (x Wq^T + bq) * scale ; kv = mem Wkv^T + bkv ; per-head
//        softmax(q k^T + rpb_bias) v ; out = o Wp^T + bp
// Shapes: B=4096, T=2, N=49 tokens, C=192, H=6 heads, d=32.
// Strategy: one block per (b,t), 512 threads (8 waves), all GEMMs via
// v_mfma_f32_16x16x32_f16 (fp32 accum). f16 chosen over bf16: same fragment
// geometry, 3 more mantissa bits, values are tiny (|x|<~6) so no range risk.
// ---------------------------------------------------------------------------

typedef _Float16 half8  __attribute__((ext_vector_type(8)));  // 4 VGPRs, one MFMA A/B frag
typedef _Float16 half4_t __attribute__((ext_vector_type(4)));
typedef float    f32x4  __attribute__((ext_vector_type(4)));  // MFMA C/D frag
typedef float    f4     __attribute__((ext_vector_type(4)));

#define NTOK  49
#define CDIM  192
#define NHEAD 6
#define SCALE 0.17677669529663687f   // 1/sqrt(32)

// ws layout (bytes):
//   WQ   f16[192*192]          @ 0       (73728)   scale folded in
//   WKV  f16[384*192]          @ 73728   (147456)
//   WPJ  f16[192*192]          @ 221184  (73728)
//   BQ   f32[192]              @ 294912  (768)     scale folded in
//   BIAS f32[6][64][64]        @ 295680  (98304)   rpb gathered via REL_IDX
// total 393984 B

__global__ void pack_kernel(const float* __restrict__ wq, const float* __restrict__ bq,
                            const float* __restrict__ wkv, const float* __restrict__ wproj,
                            const float* __restrict__ rpb,
                            _Float16* __restrict__ WQ, _Float16* __restrict__ WKV,
                            _Float16* __restrict__ WPJ, float* __restrict__ BQ,
                            float* __restrict__ BIAS)
{
    int i = blockIdx.x * blockDim.x + threadIdx.x;
    if (i < 36864) {
        WQ[i] = (_Float16)(wq[i] * SCALE);
    } else if (i < 110592) {
        int j = i - 36864;  WKV[j] = (_Float16)wkv[j];
    } else if (i < 147456) {
        int j = i - 110592; WPJ[j] = (_Float16)wproj[j];
    } else if (i < 147648) {
        int j = i - 147456; BQ[j] = bq[j] * SCALE;
    } else if (i < 147648 + 24576) {
        int j = i - 147648;
        int h  = j >> 12;        // /4096
        int qt = (j >> 6) & 63;
        int kt = j & 63;
        float v = 0.f;
        if (qt < NTOK && kt < NTOK) {
            int ih = qt / 7, iw = qt % 7, jh = kt / 7, jw = kt % 7;
            int rel = (ih - jh + 6) * 13 + (iw - jw + 6);
            v = rpb[rel * NHEAD + h];
        }
        BIAS[j] = v;
    }
}

// Fragment conventions (m89/m120-verified, 16x16x32):
//   A frag: lane holds A[m = lane&15][k = (lane>>4)*8 + j], j=0..7  (contig 16B)
//   B frag: lane holds B[k = (lane>>4)*8 + j][n = lane&15]          (contig 16B in [n][k] storage)
//   D frag: lane holds D[row = (lane>>4)*4 + r][col = lane&15]

__launch_bounds__(512)
__global__ void attn_kernel(const float* __restrict__ x, const float* __restrict__ memory,
                            const float* __restrict__ bkv, const float* __restrict__ bproj,
                            const _Float16* __restrict__ WQ, const _Float16* __restrict__ WKV,
                            const _Float16* __restrict__ WPJ, const float* __restrict__ BQ,
                            const float* __restrict__ BIAS, float* __restrict__ out)
{
    // Row strides padded: 200 f16 = 400 B (16B-aligned, stride 100 dw == 4 mod 32 -> 2-way, free)
    __shared__ __align__(16) _Float16 XM[64][200];     // x -> mem -> attention output O
    __shared__ __align__(16) _Float16 Qs[64][200];     // q*scale + bq   [tok][feat]
    __shared__ __align__(16) _Float16 Ks[64][200];     // k + bkv        [tok][feat]
    __shared__ __align__(16) _Float16 Vs[192][72];     // v + bkv        [feat][tok] (transposed)
    __shared__ __align__(16) _Float16 Ps[2][64][72];   // softmax probs  [qt][kt], per concurrent head

    const int tid  = threadIdx.x;
    const int lane = tid & 63;
    const int wave = tid >> 6;          // 0..7
    const int l16  = lane & 15;
    const int lq   = lane >> 4;         // quad 0..3
    const int bt   = blockIdx.x;        // b*2 + t
    const int b    = bt >> 1;

    const f32x4 zf = {0.f, 0.f, 0.f, 0.f};

    auto load_tile = [&](const float* src) {   // 49x192 f32 -> f16 LDS tile
        for (int t = tid; t < NTOK * CDIM / 4; t += 512) {
            int row = t / 48, c4 = (t % 48) * 4;
            f4 v = *(const f4*)(src + row * CDIM + c4);
            half4_t h; h[0] = (_Float16)v[0]; h[1] = (_Float16)v[1];
                       h[2] = (_Float16)v[2]; h[3] = (_Float16)v[3];
            *(half4_t*)&XM[row][c4] = h;
        }
    };

    // zero pad rows 49..63 once (K/V pad tokens become finite bias; masked later)
    for (int idx = tid; idx < 15 * 200; idx += 512)
        XM[49 + idx / 200][idx % 200] = (_Float16)0.f;

    load_tile(x + (size_t)b * NTOK * CDIM);
    __syncthreads();

    // ---- Q = XM @ WQ^T + BQ -> Qs.  48 (mt,nt) tiles, 6 per wave. ----
    {
        const int tt0 = wave * 6, nt0 = tt0 >> 2;
        f32x4 acc[6];
        for (int i = 0; i < 6; ++i) acc[i] = zf;
        for (int ks = 0; ks < 6; ++ks) {
            const int k0 = ks * 32 + lq * 8;
            half8 a[4];
            for (int mt = 0; mt < 4; ++mt) a[mt] = *(const half8*)&XM[mt * 16 + l16][k0];
            half8 bb[2];
            for (int j = 0; j < 2; ++j)
                bb[j] = *(const half8*)(WQ + ((nt0 + j) * 16 + l16) * CDIM + k0);
            for (int i = 0; i < 6; ++i) {
                int tt = tt0 + i;
                acc[i] = __builtin_amdgcn_mfma_f32_16x16x32_f16(a[tt & 3], bb[(tt >> 2) - nt0], acc[i], 0, 0, 0);
            }
        }
        for (int i = 0; i < 6; ++i) {
            int tt = tt0 + i, nt = tt >> 2, mt = tt & 3;
            float bv = BQ[nt * 16 + l16];
            for (int r = 0; r < 4; ++r)
                Qs[mt * 16 + lq * 4 + r][nt * 16 + l16] = (_Float16)(acc[i][r] + bv);
        }
    }
    __syncthreads();

    load_tile(memory + (size_t)bt * NTOK * CDIM);
    __syncthreads();

    // ---- K,V = XM @ WKV^T + bkv.  96 tiles over 24 n-tiles (0..11 K, 12..23 V), 12/wave ----
    {
        const int tt0 = wave * 12, nc0 = wave * 3;
        f32x4 acc[12];
        for (int i = 0; i < 12; ++i) acc[i] = zf;
        for (int ks = 0; ks < 6; ++ks) {
            const int k0 = ks * 32 + lq * 8;
            half8 a[4];
            for (int mt = 0; mt < 4; ++mt) a[mt] = *(const half8*)&XM[mt * 16 + l16][k0];
            half8 bb[3];
            for (int j = 0; j < 3; ++j)
                bb[j] = *(const half8*)(WKV + ((nc0 + j) * 16 + l16) * CDIM + k0);
            for (int i = 0; i < 12; ++i) {
                int tt = tt0 + i;
                acc[i] = __builtin_amdgcn_mfma_f32_16x16x32_f16(a[tt & 3], bb[(tt >> 2) - nc0], acc[i], 0, 0, 0);
            }
        }
        for (int i = 0; i < 12; ++i) {
            int tt = tt0 + i, ntc = tt >> 2, mt = tt & 3;
            int f = ntc * 16 + l16;            // 0..383: K feats then V feats (matches w_kv rows)
            float bv = bkv[f];
            if (ntc < 12) {
                for (int r = 0; r < 4; ++r)
                    Ks[mt * 16 + lq * 4 + r][f] = (_Float16)(acc[i][r] + bv);
            } else {
                half4_t pk;
                for (int r = 0; r < 4; ++r) pk[r] = (_Float16)(acc[i][r] + bv);
                *(half4_t*)&Vs[f - 192][mt * 16 + lq * 4] = pk;   // transposed store, 4 contig toks
            }
        }
    }
    __syncthreads();

    // ---- attention: 3 sequential head pairs; wave = (h2 = wave>>2, mt = wave&3) ----
    {
        const int h2 = wave >> 2, mt = wave & 3;
        const int row0 = mt * 16 + lq * 4;
        for (int p = 0; p < 3; ++p) {
            const int h = p * 2 + h2;
            // S = q k^T (K=32 -> single MFMA per n-tile)
            f32x4 s[4];
            half8 qa = *(const half8*)&Qs[mt * 16 + l16][h * 32 + lq * 8];
            for (int nt = 0; nt < 4; ++nt) {
                half8 kb = *(const half8*)&Ks[nt * 16 + l16][h * 32 + lq * 8];
                s[nt] = __builtin_amdgcn_mfma_f32_16x16x32_f16(qa, kb, zf, 0, 0, 0);
            }
            // + relative-position bias
            for (int nt = 0; nt < 4; ++nt)
                for (int r = 0; r < 4; ++r)
                    s[nt][r] += BIAS[(h * 64 + row0 + r) * 64 + nt * 16 + l16];
            // softmax per row (row = row0+r; cols spread over l16 x 4 n-tiles; kt>=49 masked)
            for (int r = 0; r < 4; ++r) {
                float v0 = s[0][r], v1 = s[1][r], v2 = s[2][r], v3 = s[3][r];
                float v3m = (l16 == 0) ? v3 : -3.0e38f;      // nt=3: only kt=48 valid
                float m = fmaxf(fmaxf(v0, v1), fmaxf(v2, v3m));
                for (int d2 = 1; d2 < 16; d2 <<= 1) m = fmaxf(m, __shfl_xor(m, d2, 64));
                v0 = __expf(v0 - m); v1 = __expf(v1 - m); v2 = __expf(v2 - m);
                v3 = (l16 == 0) ? __expf(v3 - m) : 0.f;
                float sm = v0 + v1 + v2 + v3;
                for (int d2 = 1; d2 < 16; d2 <<= 1) sm += __shfl_xor(sm, d2, 64);
                float inv = 1.f / sm;
                int rr = row0 + r;
                Ps[h2][rr][l16]      = (_Float16)(v0 * inv);
                Ps[h2][rr][16 + l16] = (_Float16)(v1 * inv);
                Ps[h2][rr][32 + l16] = (_Float16)(v2 * inv);
                Ps[h2][rr][48 + l16] = (_Float16)(v3 * inv);
            }
            __syncthreads();   // Ps D-layout write -> A-layout read (conservative)
            // O = P @ V
            f32x4 o0 = zf, o1 = zf;
            for (int ks2 = 0; ks2 < 2; ++ks2) {
                half8 pa  = *(const half8*)&Ps[h2][mt * 16 + l16][ks2 * 32 + lq * 8];
                half8 vb0 = *(const half8*)&Vs[h * 32 + l16][ks2 * 32 + lq * 8];
                half8 vb1 = *(const half8*)&Vs[h * 32 + 16 + l16][ks2 * 32 + lq * 8];
                o0 = __builtin_amdgcn_mfma_f32_16x16x32_f16(pa, vb0, o0, 0, 0, 0);
                o1 = __builtin_amdgcn_mfma_f32_16x16x32_f16(pa, vb1, o1, 0, 0, 0);
            }
            for (int r = 0; r < 4; ++r) {     // O -> XM (proj A operand), disjoint per wave
                XM[row0 + r][h * 32 + l16]      = (_Float16)o0[r];
                XM[row0 + r][h * 32 + 16 + l16] = (_Float16)o1[r];
            }
        }
    }
    __syncthreads();

    // ---- out = O @ WPJ^T + bproj ----
    {
        const int tt0 = wave * 6, nt0 = tt0 >> 2;
        f32x4 acc[6];
        for (int i = 0; i < 6; ++i) acc[i] = zf;
        for (int ks = 0; ks < 6; ++ks) {
            const int k0 = ks * 32 + lq * 8;
            half8 a[4];
            for (int mt = 0; mt < 4; ++mt) a[mt] = *(const half8*)&XM[mt * 16 + l16][k0];
            half8 bb[2];
            for (int j = 0; j < 2; ++j)
                bb[j] = *(const half8*)(WPJ + ((nt0 + j) * 16 + l16) * CDIM + k0);
            for (int i = 0; i < 6; ++i) {
                int tt = tt0 + i;
                acc[i] = __builtin_amdgcn_mfma_f32_16x16x32_f16(a[tt & 3], bb[(tt >> 2) - nt0], acc[i], 0, 0, 0);
            }
        }
        float* obase = out + (size_t)bt * NTOK * CDIM;
        for (int i = 0; i < 6; ++i) {
            int tt = tt0 + i, nt = tt >> 2, mt = tt & 3;
            float bv = bproj[nt * 16 + l16];
            for (int r = 0; r < 4; ++r) {
                int rr = mt * 16 + lq * 4 + r;
                if (rr < NTOK)
                    obase[rr * CDIM + nt * 16 + l16] = acc[i][r] + bv;
            }
        }
    }
}

extern "C" void kernel_launch(void* const* d_in, const int* in_sizes, int n_in,
                              void* d_out, int out_size, void* d_ws, size_t ws_size,
                              hipStream_t stream)
{
    const float* x      = (const float*)d_in[0];
    const float* memory = (const float*)d_in[1];
    const float* w_q    = (const float*)d_in[2];
    const float* b_q    = (const float*)d_in[3];
    const float* w_kv   = (const float*)d_in[4];
    const float* b_kv   = (const float*)d_in[5];
    const float* w_proj = (const float*)d_in[6];
    const float* b_proj = (const float*)d_in[7];
    const float* rpb    = (const float*)d_in[8];
    float* out = (float*)d_out;

    char* wsp = (char*)d_ws;
    _Float16* WQ  = (_Float16*)(wsp + 0);
    _Float16* WKV = (_Float16*)(wsp + 73728);
    _Float16* WPJ = (_Float16*)(wsp + 221184);
    float*    BQ  = (float*)(wsp + 294912);
    float*    BIAS= (float*)(wsp + 295680);

    pack_kernel<<<673, 256, 0, stream>>>(w_q, b_q, w_kv, w_proj, rpb, WQ, WKV, WPJ, BQ, BIAS);
    attn_kernel<<<4096 * 2, 512, 0, stream>>>(x, memory, b_kv, b_proj, WQ, WKV, WPJ, BQ, BIAS, out);
}